// Round 1
// 2864.881 us; speedup vs baseline: 3.1218x; 3.1218x over previous
//
#include <hip/hip_runtime.h>
#include <hip/hip_bf16.h>

// Problem constants
#define TB_ 1024          // T
#define BB_ 2             // B
#define MM_ 2048          // B*T rows
#define CC_ 1024          // C
#define HH_ 16            // heads
#define DD_ 64            // head dim
#define LL_ 8             // layers
#define HID_ 4096
#define VV_ 32000

typedef short short8 __attribute__((ext_vector_type(8)));
typedef short short4v __attribute__((ext_vector_type(4)));
typedef float f32x4 __attribute__((ext_vector_type(4)));
typedef unsigned short ushort;

__device__ __forceinline__ float gelu_f(float x) {
    return 0.5f * x * (1.0f + erff(x * 0.70710678118654752f));
}

// fp32 -> bf16 bits, round-to-nearest-even
__device__ __forceinline__ ushort f2bf(float x) {
    union { float f; unsigned u; } v; v.f = x;
    unsigned r = v.u + 0x7FFF + ((v.u >> 16) & 1);
    return (ushort)(r >> 16);
}

// async global->LDS, 16B per lane; lds dest must be wave-uniform base (+lane*16 by HW)
__device__ __forceinline__ void load_lds16(const void* g, void* l) {
    __builtin_amdgcn_global_load_lds(
        (__attribute__((address_space(1))) void*)(uintptr_t)g,
        (__attribute__((address_space(3))) void*)(uintptr_t)l, 16, 0, 0);
}

// -------------------- embedding: x = tok_emb[idx] + pos_emb --------------------
__global__ __launch_bounds__(256) void embed_kernel(
    const int* __restrict__ idx, const float4* __restrict__ tok,
    const float4* __restrict__ pos, float4* __restrict__ x) {
    int row = blockIdx.x;
    int t   = row & (TB_ - 1);
    int tid = threadIdx.x;
    int id  = idx[row];
    float4 a = tok[(size_t)id * 256 + tid];
    float4 p = pos[(size_t)t  * 256 + tid];
    float4 r; r.x = a.x + p.x; r.y = a.y + p.y; r.z = a.z + p.z; r.w = a.w + p.w;
    x[(size_t)row * 256 + tid] = r;
}

// -------------------- layernorm over C=1024, fp32 in, bf16 out --------------------
__global__ __launch_bounds__(256) void ln_kernel(
    const float* __restrict__ x, const float* __restrict__ g,
    const float* __restrict__ bb, ushort* __restrict__ o) {
    int row = blockIdx.x;
    int tid = threadIdx.x;
    const float* xr = x + (size_t)row * CC_;
    float v[4];
    float s = 0.f;
    #pragma unroll
    for (int i = 0; i < 4; ++i) { v[i] = xr[tid + 256 * i]; s += v[i]; }
    #pragma unroll
    for (int off = 32; off > 0; off >>= 1) s += __shfl_xor(s, off);
    __shared__ float r1[4], r2[4];
    int wid = tid >> 6;
    if ((tid & 63) == 0) r1[wid] = s;
    __syncthreads();
    float mean = (r1[0] + r1[1] + r1[2] + r1[3]) * (1.f / CC_);
    float s2 = 0.f;
    #pragma unroll
    for (int i = 0; i < 4; ++i) { float d = v[i] - mean; s2 += d * d; }
    #pragma unroll
    for (int off = 32; off > 0; off >>= 1) s2 += __shfl_xor(s2, off);
    if ((tid & 63) == 0) r2[wid] = s2;
    __syncthreads();
    float var  = (r2[0] + r2[1] + r2[2] + r2[3]) * (1.f / CC_);
    float rstd = rsqrtf(var + 1e-5f);
    #pragma unroll
    for (int i = 0; i < 4; ++i) {
        int c = tid + 256 * i;
        o[(size_t)row * CC_ + c] = f2bf((v[i] - mean) * rstd * g[c] + bb[c]);
    }
}

// ------------- weight transpose+convert: fp32 [K,N] -> bf16 [N,K] -------------
__global__ __launch_bounds__(256) void convt_kernel(
    const float* __restrict__ w, ushort* __restrict__ o, int K, int N) {
    __shared__ ushort t[64][65];
    int n0 = blockIdx.x * 64, k0 = blockIdx.y * 64;
    int tid = threadIdx.x;
    #pragma unroll
    for (int i = 0; i < 4; ++i) {
        int seg = tid + i * 256;          // 1024 segs = 64 rows * 16 float4
        int r = seg >> 4, c4 = (seg & 15) * 4;
        float4 v = *(const float4*)(w + (size_t)(k0 + r) * N + n0 + c4);
        t[r][c4 + 0] = f2bf(v.x); t[r][c4 + 1] = f2bf(v.y);
        t[r][c4 + 2] = f2bf(v.z); t[r][c4 + 3] = f2bf(v.w);
    }
    __syncthreads();
    #pragma unroll
    for (int i = 0; i < 2; ++i) {
        int seg = tid + i * 256;          // 512 segs = 64 n-rows * 8 chunks
        int n = seg >> 3, k8 = (seg & 7) * 8;
        short8 p;
        #pragma unroll
        for (int j = 0; j < 8; ++j) p[j] = (short)t[k8 + j][n];
        *(short8*)(o + (size_t)(n0 + n) * K + k0 + k8) = p;
    }
}

// -------------------- MFMA GEMM: C = A[M,K](bf16) @ Bt[N,K]^T --------------------
// BSRC=0: Bt is bf16 [N,K] (global_load_lds).  BSRC=1: Bt is fp32 [N,K] (reg staging).
// grid = (M/128, N/128). 256 threads = 4 waves, each wave 64x64 (4x4 of 16x16x32).
template <int BSRC, bool BIASF, bool GELUF, bool RESF, bool OBF16>
__global__ __launch_bounds__(256) void mgemm(
    const ushort* __restrict__ A, const void* __restrict__ Bv,
    const float* __restrict__ bias, const float* __restrict__ res,
    void* __restrict__ Cp, int M, int N, int K) {
    __shared__ ushort As[128 * 32];
    __shared__ ushort Bs[128 * 32];
    int tid = threadIdx.x;
    int lane = tid & 63, wv = tid >> 6;
    int row0 = blockIdx.x * 128, col0 = blockIdx.y * 128;
    int wr = (wv >> 1) * 64, wc = (wv & 1) * 64;
    const ushort* Bb = (const ushort*)Bv;
    const float*  Bf = (const float*)Bv;
    f32x4 acc[4][4];
    #pragma unroll
    for (int i = 0; i < 4; ++i)
        #pragma unroll
        for (int j = 0; j < 4; ++j)
            acc[i][j] = (f32x4){0.f, 0.f, 0.f, 0.f};

    for (int k0 = 0; k0 < K; k0 += 32) {
        // A tile 128x32 bf16 via async direct-to-LDS (contiguous [row][k] layout)
        #pragma unroll
        for (int it = 0; it < 2; ++it) {
            int seg = it * 256 + tid;                // 512 segs of 16B
            int r = seg >> 2, c8 = (seg & 3) * 8;
            load_lds16(A + (size_t)(row0 + r) * K + k0 + c8,
                       &As[(size_t)(it * 256 + wv * 64) * 8]);
        }
        if (BSRC == 0) {
            #pragma unroll
            for (int it = 0; it < 2; ++it) {
                int seg = it * 256 + tid;
                int n = seg >> 2, c8 = (seg & 3) * 8;
                load_lds16(Bb + (size_t)(col0 + n) * K + k0 + c8,
                           &Bs[(size_t)(it * 256 + wv * 64) * 8]);
            }
        } else {
            #pragma unroll
            for (int it = 0; it < 4; ++it) {
                int seg = it * 256 + tid;            // 1024 segs of float4
                int n = seg >> 3, c4 = (seg & 7) * 4;
                float4 v = *(const float4*)(Bf + (size_t)(col0 + n) * K + k0 + c4);
                short4v p;
                p[0] = (short)f2bf(v.x); p[1] = (short)f2bf(v.y);
                p[2] = (short)f2bf(v.z); p[3] = (short)f2bf(v.w);
                *(short4v*)&Bs[n * 32 + c4] = p;
            }
        }
        __syncthreads();
        short8 af[4], bfv[4];
        #pragma unroll
        for (int i = 0; i < 4; ++i)
            af[i] = *(const short8*)&As[(wr + i * 16 + (lane & 15)) * 32 + (lane >> 4) * 8];
        #pragma unroll
        for (int j = 0; j < 4; ++j)
            bfv[j] = *(const short8*)&Bs[(wc + j * 16 + (lane & 15)) * 32 + (lane >> 4) * 8];
        #pragma unroll
        for (int i = 0; i < 4; ++i)
            #pragma unroll
            for (int j = 0; j < 4; ++j)
                acc[i][j] = __builtin_amdgcn_mfma_f32_16x16x32_bf16(
                    af[i], bfv[j], acc[i][j], 0, 0, 0);
        __syncthreads();
    }

    float* Co = (float*)Cp;
    ushort* Cb = (ushort*)Cp;
    #pragma unroll
    for (int i = 0; i < 4; ++i) {
        #pragma unroll
        for (int j = 0; j < 4; ++j) {
            #pragma unroll
            for (int r = 0; r < 4; ++r) {
                int row = row0 + wr + i * 16 + (lane >> 4) * 4 + r;
                int col = col0 + wc + j * 16 + (lane & 15);
                float v = acc[i][j][r];
                if (BIASF) v += bias[col];
                if (GELUF) v = gelu_f(v);
                if (RESF)  v += res[(size_t)row * N + col];
                if (OBF16) Cb[(size_t)row * N + col] = f2bf(v);
                else       Co[(size_t)row * N + col] = v;
            }
        }
    }
}

// -------------------- flash-style MFMA attention --------------------
// qkv bf16 [B*T, 3C]; out bf16 [B*T, C] head h at col h*64.
// grid (T/64, B*H), 256 threads = 4 waves; wave wv owns queries qt*64+wv*16 .. +15.
// Per KV tile of 64: QK^T (K-frags straight from global, L2-resident),
// online softmax in C-frag layout, P->LDS transpose (XOR-swizzled),
// V^T staged in XOR-swizzled LDS, PV via MFMA.
__global__ __launch_bounds__(256) void fattn_kernel(
    const ushort* __restrict__ qkv, ushort* __restrict__ att) {
    __shared__ ushort Vt[64 * 64];        // V^T, idx = d*64 + (kv ^ ((d&7)<<3))
    __shared__ ushort Pl[4][16 * 64];     // per-wave P, idx = q*64 + (kv ^ ((q&7)<<3))
    int qt = blockIdx.x;
    int b  = blockIdx.y >> 4, h = blockIdx.y & 15;
    int tid = threadIdx.x, lane = tid & 63, wv = tid >> 6;
    int lr = lane & 15, lg = lane >> 4;
    const int C3 = 3 * CC_;
    const ushort* base = qkv + (size_t)b * TB_ * C3 + h * DD_;
    const ushort* kb = base + CC_;
    const ushort* vb = base + 2 * CC_;
    int q0 = qt * 64 + wv * 16;

    // Q A-frags (row = q0+lr, k = lg*8+j), d-chunks 0 and 32
    short8 qf[2];
    #pragma unroll
    for (int kc = 0; kc < 2; ++kc)
        qf[kc] = *(const short8*)(base + (size_t)(q0 + lr) * C3 + kc * 32 + lg * 8);

    float m[4], l[4];
    f32x4 o[4];
    #pragma unroll
    for (int r = 0; r < 4; ++r) { m[r] = -1e30f; l[r] = 0.f; }
    #pragma unroll
    for (int dt = 0; dt < 4; ++dt) o[dt] = (f32x4){0.f, 0.f, 0.f, 0.f};

    // V^T staging assignment: wave wv stages d-rows [wv*16, wv*16+16), kv = lane
    int sdb = wv * 16;

    for (int kt = 0; kt <= qt; ++kt) {
        __syncthreads();   // protect Vt from previous iteration's PV reads
        {   // stage V^T (swizzled): conflict-free (whole wave writes one d-row/instr)
            const ushort* vrow = vb + (size_t)(kt * 64 + lane) * C3 + sdb;
            short8 v0 = *(const short8*)(vrow);
            short8 v1 = *(const short8*)(vrow + 8);
            #pragma unroll
            for (int j = 0; j < 8; ++j) {
                int d0 = sdb + j, d1 = sdb + 8 + j;
                Vt[d0 * 64 + (lane ^ ((d0 & 7) << 3))] = (ushort)v0[j];
                Vt[d1 * 64 + (lane ^ ((d1 & 7) << 3))] = (ushort)v1[j];
            }
        }
        // S = Q @ K^T for this wave's 16 queries x 64 kv (overlaps Vt staging)
        f32x4 s[4];
        #pragma unroll
        for (int ct = 0; ct < 4; ++ct) s[ct] = (f32x4){0.f, 0.f, 0.f, 0.f};
        #pragma unroll
        for (int ct = 0; ct < 4; ++ct) {
            const ushort* kr = kb + (size_t)(kt * 64 + ct * 16 + lr) * C3 + lg * 8;
            short8 b0 = *(const short8*)(kr);
            short8 b1 = *(const short8*)(kr + 32);
            s[ct] = __builtin_amdgcn_mfma_f32_16x16x32_bf16(qf[0], b0, s[ct], 0, 0, 0);
            s[ct] = __builtin_amdgcn_mfma_f32_16x16x32_bf16(qf[1], b1, s[ct], 0, 0, 0);
        }
        // scale + causal mask (diagonal tile only; tile base == q-tile base)
        float sv[4][4];
        #pragma unroll
        for (int ct = 0; ct < 4; ++ct)
            #pragma unroll
            for (int r = 0; r < 4; ++r)
                sv[ct][r] = s[ct][r] * 0.125f;
        if (kt == qt) {
            #pragma unroll
            for (int ct = 0; ct < 4; ++ct) {
                int kvg = ct * 16 + lr;
                #pragma unroll
                for (int r = 0; r < 4; ++r) {
                    int qg = wv * 16 + lg * 4 + r;
                    if (kvg > qg) sv[ct][r] = -1e30f;
                }
            }
        }
        // online softmax: row max -> rescale -> p -> row sum
        #pragma unroll
        for (int r = 0; r < 4; ++r) {
            float mx = fmaxf(fmaxf(sv[0][r], sv[1][r]), fmaxf(sv[2][r], sv[3][r]));
            #pragma unroll
            for (int off = 1; off < 16; off <<= 1) mx = fmaxf(mx, __shfl_xor(mx, off));
            float mn = fmaxf(m[r], mx);
            float al = __expf(m[r] - mn);
            m[r] = mn;
            l[r] *= al;
            #pragma unroll
            for (int dt = 0; dt < 4; ++dt) o[dt][r] *= al;
        }
        float ps[4] = {0.f, 0.f, 0.f, 0.f};
        #pragma unroll
        for (int ct = 0; ct < 4; ++ct)
            #pragma unroll
            for (int r = 0; r < 4; ++r) {
                float p = __expf(sv[ct][r] - m[r]);
                ps[r] += p;
                int qr = lg * 4 + r;
                Pl[wv][qr * 64 + ((ct * 16 + lr) ^ ((qr & 7) << 3))] = f2bf(p);
            }
        #pragma unroll
        for (int r = 0; r < 4; ++r) {
            float t = ps[r];
            #pragma unroll
            for (int off = 1; off < 16; off <<= 1) t += __shfl_xor(t, off);
            l[r] += t;
        }
        __syncthreads();   // Vt staged by all waves
        // PV: o += P @ V  (A = P from Pl, B = V from Vt, both swizzle-read)
        #pragma unroll
        for (int kc = 0; kc < 2; ++kc) {
            short8 pa = *(const short8*)
                &Pl[wv][lr * 64 + ((kc * 32 + lg * 8) ^ ((lr & 7) << 3))];
            #pragma unroll
            for (int dt = 0; dt < 4; ++dt) {
                int d = dt * 16 + lr;
                short8 vf = *(const short8*)
                    &Vt[d * 64 + ((kc * 32 + lg * 8) ^ ((d & 7) << 3))];
                o[dt] = __builtin_amdgcn_mfma_f32_16x16x32_bf16(pa, vf, o[dt], 0, 0, 0);
            }
        }
    }

    float inv[4];
    #pragma unroll
    for (int r = 0; r < 4; ++r) inv[r] = 1.0f / l[r];
    size_t orow = (size_t)(b * TB_ + q0);
    #pragma unroll
    for (int dt = 0; dt < 4; ++dt)
        #pragma unroll
        for (int r = 0; r < 4; ++r)
            att[(orow + lg * 4 + r) * CC_ + h * DD_ + dt * 16 + lr] =
                f2bf(o[dt][r] * inv[r]);
}

extern "C" void kernel_launch(void* const* d_in, const int* in_sizes, int n_in,
                              void* d_out, int out_size, void* d_ws, size_t ws_size,
                              hipStream_t stream) {
    const int*   idx     = (const int*)  d_in[0];
    const float* tok_emb = (const float*)d_in[1];
    const float* pos_emb = (const float*)d_in[2];
    const float* qkv_w   = (const float*)d_in[3];
    const float* proj_w  = (const float*)d_in[4];
    const float* proj_b  = (const float*)d_in[5];
    const float* ln1_g   = (const float*)d_in[6];
    const float* ln1_b   = (const float*)d_in[7];
    const float* ln2_g   = (const float*)d_in[8];
    const float* ln2_b   = (const float*)d_in[9];
    const float* fc1_w   = (const float*)d_in[10];
    const float* fc1_b   = (const float*)d_in[11];
    const float* fc2_w   = (const float*)d_in[12];
    const float* fc2_b   = (const float*)d_in[13];
    const float* lnf_g   = (const float*)d_in[14];
    const float* lnf_b   = (const float*)d_in[15];
    float* out = (float*)d_out;

    // workspace layout (bytes):
    // x fp32 8MB | qkvbuf bf16 12MB (region sized 24MB) | abuf1 bf16 4MB |
    // abuf2 bf16 16MB | wbuf bf16 8.4MB
    char* w = (char*)d_ws;
    float*  x      = (float*)w;                          w += (size_t)MM_ * CC_ * 4;
    ushort* qkvbuf = (ushort*)w;                         w += (size_t)MM_ * 3 * CC_ * 4;
    ushort* abuf1  = (ushort*)w;                         w += (size_t)MM_ * CC_ * 2;
    ushort* abuf2  = (ushort*)w;                         w += (size_t)MM_ * HID_ * 2;
    ushort* wbuf   = (ushort*)w;

    embed_kernel<<<MM_, 256, 0, stream>>>(idx, (const float4*)tok_emb,
                                          (const float4*)pos_emb, (float4*)x);
    for (int l = 0; l < LL_; ++l) {
        // h = LN1(x) -> bf16
        ln_kernel<<<MM_, 256, 0, stream>>>(x, ln1_g + l * CC_, ln1_b + l * CC_, abuf1);
        // qkv = h @ qkv_w (no bias), bf16 out
        convt_kernel<<<dim3(3 * CC_ / 64, CC_ / 64), 256, 0, stream>>>(
            qkv_w + (size_t)l * CC_ * 3 * CC_, wbuf, CC_, 3 * CC_);
        mgemm<0, false, false, false, true><<<dim3(MM_ / 128, 3 * CC_ / 128), 256, 0, stream>>>(
            abuf1, wbuf, nullptr, nullptr, qkvbuf, MM_, 3 * CC_, CC_);
        // att -> bf16 (flash MFMA attention)
        fattn_kernel<<<dim3(TB_ / 64, BB_ * HH_), 256, 0, stream>>>(qkvbuf, abuf1);
        // x = x + att @ proj_w + proj_b
        convt_kernel<<<dim3(CC_ / 64, CC_ / 64), 256, 0, stream>>>(
            proj_w + (size_t)l * CC_ * CC_, wbuf, CC_, CC_);
        mgemm<0, true, false, true, false><<<dim3(MM_ / 128, CC_ / 128), 256, 0, stream>>>(
            abuf1, wbuf, proj_b + l * CC_, x, x, MM_, CC_, CC_);
        // h = LN2(x) -> bf16
        ln_kernel<<<MM_, 256, 0, stream>>>(x, ln2_g + l * CC_, ln2_b + l * CC_, abuf1);
        // hid = gelu(h @ fc1_w + fc1_b) -> bf16
        convt_kernel<<<dim3(HID_ / 64, CC_ / 64), 256, 0, stream>>>(
            fc1_w + (size_t)l * CC_ * HID_, wbuf, CC_, HID_);
        mgemm<0, true, true, false, true><<<dim3(MM_ / 128, HID_ / 128), 256, 0, stream>>>(
            abuf1, wbuf, fc1_b + l * HID_, nullptr, abuf2, MM_, HID_, CC_);
        // x = x + hid @ fc2_w + fc2_b
        convt_kernel<<<dim3(CC_ / 64, HID_ / 64), 256, 0, stream>>>(
            fc2_w + (size_t)l * HID_ * CC_, wbuf, HID_, CC_);
        mgemm<0, true, false, true, false><<<dim3(MM_ / 128, CC_ / 128), 256, 0, stream>>>(
            abuf2, wbuf, fc2_b + l * CC_, x, x, MM_, CC_, HID_);
    }
    // final LN + tied lm_head (tok_emb fp32 [V,C] = B^T layout, reg-staged)
    ln_kernel<<<MM_, 256, 0, stream>>>(x, lnf_g, lnf_b, abuf1);
    mgemm<1, false, false, false, false><<<dim3(MM_ / 128, VV_ / 128), 256, 0, stream>>>(
        abuf1, tok_emb, nullptr, nullptr, out, MM_, VV_, CC_);
}

// Round 2
// 2847.211 us; speedup vs baseline: 3.1412x; 1.0062x over previous
//
#include <hip/hip_runtime.h>
#include <hip/hip_bf16.h>

// Problem constants
#define TB_ 1024          // T
#define BB_ 2             // B
#define MM_ 2048          // B*T rows
#define CC_ 1024          // C
#define HH_ 16            // heads
#define DD_ 64            // head dim
#define LL_ 8             // layers
#define HID_ 4096
#define VV_ 32000

typedef short short8 __attribute__((ext_vector_type(8)));
typedef short short4v __attribute__((ext_vector_type(4)));
typedef float f32x4 __attribute__((ext_vector_type(4)));
typedef unsigned short ushort;

__device__ __forceinline__ float gelu_f(float x) {
    return 0.5f * x * (1.0f + erff(x * 0.70710678118654752f));
}

// fp32 -> bf16 bits, round-to-nearest-even
__device__ __forceinline__ ushort f2bf(float x) {
    union { float f; unsigned u; } v; v.f = x;
    unsigned r = v.u + 0x7FFF + ((v.u >> 16) & 1);
    return (ushort)(r >> 16);
}

// async global->LDS, 16B per lane; lds dest must be wave-uniform base (+lane*16 by HW)
__device__ __forceinline__ void load_lds16(const void* g, void* l) {
    __builtin_amdgcn_global_load_lds(
        (__attribute__((address_space(1))) void*)(uintptr_t)g,
        (__attribute__((address_space(3))) void*)(uintptr_t)l, 16, 0, 0);
}

// -------------------- embedding: x = tok_emb[idx] + pos_emb --------------------
__global__ __launch_bounds__(256) void embed_kernel(
    const int* __restrict__ idx, const float4* __restrict__ tok,
    const float4* __restrict__ pos, float4* __restrict__ x) {
    int row = blockIdx.x;
    int t   = row & (TB_ - 1);
    int tid = threadIdx.x;
    int id  = idx[row];
    float4 a = tok[(size_t)id * 256 + tid];
    float4 p = pos[(size_t)t  * 256 + tid];
    float4 r; r.x = a.x + p.x; r.y = a.y + p.y; r.z = a.z + p.z; r.w = a.w + p.w;
    x[(size_t)row * 256 + tid] = r;
}

// ------------- elementwise fp32 -> bf16 (8 elems/thread) -------------
__global__ __launch_bounds__(256) void cvt_bf16(
    const float4* __restrict__ in, short8* __restrict__ o) {
    size_t i = (size_t)blockIdx.x * 256 + threadIdx.x;
    float4 a = in[2 * i], b = in[2 * i + 1];
    short8 p;
    p[0] = f2bf(a.x); p[1] = f2bf(a.y); p[2] = f2bf(a.z); p[3] = f2bf(a.w);
    p[4] = f2bf(b.x); p[5] = f2bf(b.y); p[6] = f2bf(b.z); p[7] = f2bf(b.w);
    o[i] = p;
}

// -------------------- layernorm over C=1024, fp32 in, bf16 out --------------------
__global__ __launch_bounds__(256) void ln_kernel(
    const float* __restrict__ x, const float* __restrict__ g,
    const float* __restrict__ bb, ushort* __restrict__ o) {
    int row = blockIdx.x;
    int tid = threadIdx.x;
    const float* xr = x + (size_t)row * CC_;
    float v[4];
    float s = 0.f;
    #pragma unroll
    for (int i = 0; i < 4; ++i) { v[i] = xr[tid + 256 * i]; s += v[i]; }
    #pragma unroll
    for (int off = 32; off > 0; off >>= 1) s += __shfl_xor(s, off);
    __shared__ float r1[4], r2[4];
    int wid = tid >> 6;
    if ((tid & 63) == 0) r1[wid] = s;
    __syncthreads();
    float mean = (r1[0] + r1[1] + r1[2] + r1[3]) * (1.f / CC_);
    float s2 = 0.f;
    #pragma unroll
    for (int i = 0; i < 4; ++i) { float d = v[i] - mean; s2 += d * d; }
    #pragma unroll
    for (int off = 32; off > 0; off >>= 1) s2 += __shfl_xor(s2, off);
    if ((tid & 63) == 0) r2[wid] = s2;
    __syncthreads();
    float var  = (r2[0] + r2[1] + r2[2] + r2[3]) * (1.f / CC_);
    float rstd = rsqrtf(var + 1e-5f);
    #pragma unroll
    for (int i = 0; i < 4; ++i) {
        int c = tid + 256 * i;
        o[(size_t)row * CC_ + c] = f2bf((v[i] - mean) * rstd * g[c] + bb[c]);
    }
}

// ------------- weight transpose+convert: fp32 [K,N] -> bf16 [N,K] -------------
// blockIdx.z = layer index (src/dst advance by K*N per layer)
__global__ __launch_bounds__(256) void convt_kernel(
    const float* __restrict__ w, ushort* __restrict__ o, int K, int N) {
    size_t lo = (size_t)blockIdx.z * K * N;
    w += lo; o += lo;
    __shared__ ushort t[64][65];
    int n0 = blockIdx.x * 64, k0 = blockIdx.y * 64;
    int tid = threadIdx.x;
    #pragma unroll
    for (int i = 0; i < 4; ++i) {
        int seg = tid + i * 256;          // 1024 segs = 64 rows * 16 float4
        int r = seg >> 4, c4 = (seg & 15) * 4;
        float4 v = *(const float4*)(w + (size_t)(k0 + r) * N + n0 + c4);
        t[r][c4 + 0] = f2bf(v.x); t[r][c4 + 1] = f2bf(v.y);
        t[r][c4 + 2] = f2bf(v.z); t[r][c4 + 3] = f2bf(v.w);
    }
    __syncthreads();
    #pragma unroll
    for (int i = 0; i < 2; ++i) {
        int seg = tid + i * 256;          // 512 segs = 64 n-rows * 8 chunks
        int n = seg >> 3, k8 = (seg & 7) * 8;
        short8 p;
        #pragma unroll
        for (int j = 0; j < 8; ++j) p[j] = (short)t[k8 + j][n];
        *(short8*)(o + (size_t)(n0 + n) * K + k0 + k8) = p;
    }
}

// -------------------- MFMA GEMM: C = A[M,K](bf16) @ Bt[N,K]^T --------------------
// BSRC=0: Bt is bf16 [N,K] (global_load_lds).  BSRC=1: Bt is fp32 [N,K] (reg staging).
// grid = (M/128, N/128). 256 threads = 4 waves, each wave 64x64 (4x4 of 16x16x32).
template <int BSRC, bool BIASF, bool GELUF, bool RESF, bool OBF16>
__global__ __launch_bounds__(256) void mgemm(
    const ushort* __restrict__ A, const void* __restrict__ Bv,
    const float* __restrict__ bias, const float* __restrict__ res,
    void* __restrict__ Cp, int M, int N, int K) {
    __shared__ ushort As[128 * 32];
    __shared__ ushort Bs[128 * 32];
    int tid = threadIdx.x;
    int lane = tid & 63, wv = tid >> 6;
    int row0 = blockIdx.x * 128, col0 = blockIdx.y * 128;
    int wr = (wv >> 1) * 64, wc = (wv & 1) * 64;
    const ushort* Bb = (const ushort*)Bv;
    const float*  Bf = (const float*)Bv;
    f32x4 acc[4][4];
    #pragma unroll
    for (int i = 0; i < 4; ++i)
        #pragma unroll
        for (int j = 0; j < 4; ++j)
            acc[i][j] = (f32x4){0.f, 0.f, 0.f, 0.f};

    for (int k0 = 0; k0 < K; k0 += 32) {
        // A tile 128x32 bf16 via async direct-to-LDS (contiguous [row][k] layout)
        #pragma unroll
        for (int it = 0; it < 2; ++it) {
            int seg = it * 256 + tid;                // 512 segs of 16B
            int r = seg >> 2, c8 = (seg & 3) * 8;
            load_lds16(A + (size_t)(row0 + r) * K + k0 + c8,
                       &As[(size_t)(it * 256 + wv * 64) * 8]);
        }
        if (BSRC == 0) {
            #pragma unroll
            for (int it = 0; it < 2; ++it) {
                int seg = it * 256 + tid;
                int n = seg >> 2, c8 = (seg & 3) * 8;
                load_lds16(Bb + (size_t)(col0 + n) * K + k0 + c8,
                           &Bs[(size_t)(it * 256 + wv * 64) * 8]);
            }
        } else {
            #pragma unroll
            for (int it = 0; it < 4; ++it) {
                int seg = it * 256 + tid;            // 1024 segs of float4
                int n = seg >> 3, c4 = (seg & 7) * 4;
                float4 v = *(const float4*)(Bf + (size_t)(col0 + n) * K + k0 + c4);
                short4v p;
                p[0] = (short)f2bf(v.x); p[1] = (short)f2bf(v.y);
                p[2] = (short)f2bf(v.z); p[3] = (short)f2bf(v.w);
                *(short4v*)&Bs[n * 32 + c4] = p;
            }
        }
        __syncthreads();
        short8 af[4], bfv[4];
        #pragma unroll
        for (int i = 0; i < 4; ++i)
            af[i] = *(const short8*)&As[(wr + i * 16 + (lane & 15)) * 32 + (lane >> 4) * 8];
        #pragma unroll
        for (int j = 0; j < 4; ++j)
            bfv[j] = *(const short8*)&Bs[(wc + j * 16 + (lane & 15)) * 32 + (lane >> 4) * 8];
        #pragma unroll
        for (int i = 0; i < 4; ++i)
            #pragma unroll
            for (int j = 0; j < 4; ++j)
                acc[i][j] = __builtin_amdgcn_mfma_f32_16x16x32_bf16(
                    af[i], bfv[j], acc[i][j], 0, 0, 0);
        __syncthreads();
    }

    float* Co = (float*)Cp;
    ushort* Cb = (ushort*)Cp;
    #pragma unroll
    for (int i = 0; i < 4; ++i) {
        #pragma unroll
        for (int j = 0; j < 4; ++j) {
            #pragma unroll
            for (int r = 0; r < 4; ++r) {
                int row = row0 + wr + i * 16 + (lane >> 4) * 4 + r;
                int col = col0 + wc + j * 16 + (lane & 15);
                float v = acc[i][j][r];
                if (BIASF) v += bias[col];
                if (GELUF) v = gelu_f(v);
                if (RESF)  v += res[(size_t)row * N + col];
                if (OBF16) Cb[(size_t)row * N + col] = f2bf(v);
                else       Co[(size_t)row * N + col] = v;
            }
        }
    }
}

// -------------------- flash-style MFMA attention --------------------
// qkv bf16 [B*T, 3C]; out bf16 [B*T, C] head h at col h*64.
// grid (T/64, B*H), 256 threads = 4 waves; wave wv owns queries qt*64+wv*16 .. +15.
__global__ __launch_bounds__(256) void fattn_kernel(
    const ushort* __restrict__ qkv, ushort* __restrict__ att) {
    __shared__ ushort Vt[64 * 64];        // V^T, idx = d*64 + (kv ^ ((d&7)<<3))
    __shared__ ushort Pl[4][16 * 64];     // per-wave P, idx = q*64 + (kv ^ ((q&7)<<3))
    int qt = blockIdx.x;
    int b  = blockIdx.y >> 4, h = blockIdx.y & 15;
    int tid = threadIdx.x, lane = tid & 63, wv = tid >> 6;
    int lr = lane & 15, lg = lane >> 4;
    const int C3 = 3 * CC_;
    const ushort* base = qkv + (size_t)b * TB_ * C3 + h * DD_;
    const ushort* kb = base + CC_;
    const ushort* vb = base + 2 * CC_;
    int q0 = qt * 64 + wv * 16;

    short8 qf[2];
    #pragma unroll
    for (int kc = 0; kc < 2; ++kc)
        qf[kc] = *(const short8*)(base + (size_t)(q0 + lr) * C3 + kc * 32 + lg * 8);

    float m[4], l[4];
    f32x4 o[4];
    #pragma unroll
    for (int r = 0; r < 4; ++r) { m[r] = -1e30f; l[r] = 0.f; }
    #pragma unroll
    for (int dt = 0; dt < 4; ++dt) o[dt] = (f32x4){0.f, 0.f, 0.f, 0.f};

    int sdb = wv * 16;

    for (int kt = 0; kt <= qt; ++kt) {
        __syncthreads();
        {   // stage V^T (swizzled)
            const ushort* vrow = vb + (size_t)(kt * 64 + lane) * C3 + sdb;
            short8 v0 = *(const short8*)(vrow);
            short8 v1 = *(const short8*)(vrow + 8);
            #pragma unroll
            for (int j = 0; j < 8; ++j) {
                int d0 = sdb + j, d1 = sdb + 8 + j;
                Vt[d0 * 64 + (lane ^ ((d0 & 7) << 3))] = (ushort)v0[j];
                Vt[d1 * 64 + (lane ^ ((d1 & 7) << 3))] = (ushort)v1[j];
            }
        }
        f32x4 s[4];
        #pragma unroll
        for (int ct = 0; ct < 4; ++ct) s[ct] = (f32x4){0.f, 0.f, 0.f, 0.f};
        #pragma unroll
        for (int ct = 0; ct < 4; ++ct) {
            const ushort* kr = kb + (size_t)(kt * 64 + ct * 16 + lr) * C3 + lg * 8;
            short8 b0 = *(const short8*)(kr);
            short8 b1 = *(const short8*)(kr + 32);
            s[ct] = __builtin_amdgcn_mfma_f32_16x16x32_bf16(qf[0], b0, s[ct], 0, 0, 0);
            s[ct] = __builtin_amdgcn_mfma_f32_16x16x32_bf16(qf[1], b1, s[ct], 0, 0, 0);
        }
        float sv[4][4];
        #pragma unroll
        for (int ct = 0; ct < 4; ++ct)
            #pragma unroll
            for (int r = 0; r < 4; ++r)
                sv[ct][r] = s[ct][r] * 0.125f;
        if (kt == qt) {
            #pragma unroll
            for (int ct = 0; ct < 4; ++ct) {
                int kvg = ct * 16 + lr;
                #pragma unroll
                for (int r = 0; r < 4; ++r) {
                    int qg = wv * 16 + lg * 4 + r;
                    if (kvg > qg) sv[ct][r] = -1e30f;
                }
            }
        }
        #pragma unroll
        for (int r = 0; r < 4; ++r) {
            float mx = fmaxf(fmaxf(sv[0][r], sv[1][r]), fmaxf(sv[2][r], sv[3][r]));
            #pragma unroll
            for (int off = 1; off < 16; off <<= 1) mx = fmaxf(mx, __shfl_xor(mx, off));
            float mn = fmaxf(m[r], mx);
            float al = __expf(m[r] - mn);
            m[r] = mn;
            l[r] *= al;
            #pragma unroll
            for (int dt = 0; dt < 4; ++dt) o[dt][r] *= al;
        }
        float ps[4] = {0.f, 0.f, 0.f, 0.f};
        #pragma unroll
        for (int ct = 0; ct < 4; ++ct)
            #pragma unroll
            for (int r = 0; r < 4; ++r) {
                float p = __expf(sv[ct][r] - m[r]);
                ps[r] += p;
                int qr = lg * 4 + r;
                Pl[wv][qr * 64 + ((ct * 16 + lr) ^ ((qr & 7) << 3))] = f2bf(p);
            }
        #pragma unroll
        for (int r = 0; r < 4; ++r) {
            float t = ps[r];
            #pragma unroll
            for (int off = 1; off < 16; off <<= 1) t += __shfl_xor(t, off);
            l[r] += t;
        }
        __syncthreads();
        #pragma unroll
        for (int kc = 0; kc < 2; ++kc) {
            short8 pa = *(const short8*)
                &Pl[wv][lr * 64 + ((kc * 32 + lg * 8) ^ ((lr & 7) << 3))];
            #pragma unroll
            for (int dt = 0; dt < 4; ++dt) {
                int d = dt * 16 + lr;
                short8 vf = *(const short8*)
                    &Vt[d * 64 + ((kc * 32 + lg * 8) ^ ((d & 7) << 3))];
                o[dt] = __builtin_amdgcn_mfma_f32_16x16x32_bf16(pa, vf, o[dt], 0, 0, 0);
            }
        }
    }

    float inv[4];
    #pragma unroll
    for (int r = 0; r < 4; ++r) inv[r] = 1.0f / l[r];
    size_t orow = (size_t)(b * TB_ + q0);
    #pragma unroll
    for (int dt = 0; dt < 4; ++dt)
        #pragma unroll
        for (int r = 0; r < 4; ++r)
            att[(orow + lg * 4 + r) * CC_ + h * DD_ + dt * 16 + lr] =
                f2bf(o[dt][r] * inv[r]);
}

extern "C" void kernel_launch(void* const* d_in, const int* in_sizes, int n_in,
                              void* d_out, int out_size, void* d_ws, size_t ws_size,
                              hipStream_t stream) {
    const int*   idx     = (const int*)  d_in[0];
    const float* tok_emb = (const float*)d_in[1];
    const float* pos_emb = (const float*)d_in[2];
    const float* qkv_w   = (const float*)d_in[3];
    const float* proj_w  = (const float*)d_in[4];
    const float* proj_b  = (const float*)d_in[5];
    const float* ln1_g   = (const float*)d_in[6];
    const float* ln1_b   = (const float*)d_in[7];
    const float* ln2_g   = (const float*)d_in[8];
    const float* ln2_b   = (const float*)d_in[9];
    const float* fc1_w   = (const float*)d_in[10];
    const float* fc1_b   = (const float*)d_in[11];
    const float* fc2_w   = (const float*)d_in[12];
    const float* fc2_b   = (const float*)d_in[13];
    const float* lnf_g   = (const float*)d_in[14];
    const float* lnf_b   = (const float*)d_in[15];
    float* out = (float*)d_out;

    const size_t C2 = (size_t)CC_ * CC_;           // 1M elems
    const size_t sz_x    = (size_t)MM_ * CC_ * 4;          // 8 MB
    const size_t sz_qkv  = (size_t)MM_ * 3 * CC_ * 2;      // 12 MB
    const size_t sz_a1   = (size_t)MM_ * CC_ * 2;          // 4 MB
    const size_t sz_a2   = (size_t)MM_ * HID_ * 2;         // 16 MB
    const size_t sz_temb = (size_t)VV_ * CC_ * 2;          // 65.5 MB
    const size_t sz_wbuf = (size_t)CC_ * HID_ * 2;         // 8.4 MB (max single weight)
    const size_t sz_wall = (size_t)LL_ * 12 * C2 * 2;      // 201 MB (all weights bf16)
    const size_t needB = sz_x + sz_qkv + sz_a1 + sz_a2 + sz_temb + sz_wbuf;
    const size_t needA = sz_x + sz_qkv + sz_a1 + sz_a2 + sz_temb + sz_wall;
    const bool haveWall = ws_size >= needA;
    const bool haveTemb = ws_size >= needB;

    char* p = (char*)d_ws;
    float*  x;
    ushort *qkvbuf, *abuf1, *abuf2;
    ushort *temb = nullptr, *wbuf = nullptr;
    ushort *wqkv = nullptr, *wproj = nullptr, *wfc1 = nullptr, *wfc2 = nullptr;

    x = (float*)p; p += sz_x;
    if (haveTemb) {
        qkvbuf = (ushort*)p; p += sz_qkv;
        abuf1  = (ushort*)p; p += sz_a1;
        abuf2  = (ushort*)p; p += sz_a2;
        temb   = (ushort*)p; p += sz_temb;
        if (haveWall) {
            wqkv  = (ushort*)p; p += (size_t)LL_ * 3 * C2 * 2;
            wproj = (ushort*)p; p += (size_t)LL_ * C2 * 2;
            wfc1  = (ushort*)p; p += (size_t)LL_ * 4 * C2 * 2;
            wfc2  = (ushort*)p; p += (size_t)LL_ * 4 * C2 * 2;
        } else {
            wbuf = (ushort*)p;
        }
    } else {
        // legacy layout (fits in 63 MB)
        qkvbuf = (ushort*)p; p += (size_t)MM_ * 3 * CC_ * 4;
        abuf1  = (ushort*)p; p += sz_a1;
        abuf2  = (ushort*)p; p += sz_a2;
        wbuf   = (ushort*)p;
    }

    embed_kernel<<<MM_, 256, 0, stream>>>(idx, (const float4*)tok_emb,
                                          (const float4*)pos_emb, (float4*)x);
    if (haveTemb)
        cvt_bf16<<<VV_ * CC_ / (256 * 8), 256, 0, stream>>>(
            (const float4*)tok_emb, (short8*)temb);
    if (haveWall) {
        // convert all weights up-front: 4 launches, blockIdx.z = layer
        convt_kernel<<<dim3(3 * CC_ / 64, CC_ / 64, LL_), 256, 0, stream>>>(
            qkv_w, wqkv, CC_, 3 * CC_);
        convt_kernel<<<dim3(CC_ / 64, CC_ / 64, LL_), 256, 0, stream>>>(
            proj_w, wproj, CC_, CC_);
        convt_kernel<<<dim3(HID_ / 64, CC_ / 64, LL_), 256, 0, stream>>>(
            fc1_w, wfc1, CC_, HID_);
        convt_kernel<<<dim3(CC_ / 64, HID_ / 64, LL_), 256, 0, stream>>>(
            fc2_w, wfc2, HID_, CC_);
    }

    for (int l = 0; l < LL_; ++l) {
        const ushort* bq = haveWall ? wqkv  + (size_t)l * 3 * C2 : wbuf;
        const ushort* bp = haveWall ? wproj + (size_t)l * C2     : wbuf;
        const ushort* b1 = haveWall ? wfc1  + (size_t)l * 4 * C2 : wbuf;
        const ushort* b2 = haveWall ? wfc2  + (size_t)l * 4 * C2 : wbuf;
        // h = LN1(x) -> bf16
        ln_kernel<<<MM_, 256, 0, stream>>>(x, ln1_g + l * CC_, ln1_b + l * CC_, abuf1);
        // qkv = h @ qkv_w (no bias), bf16 out
        if (!haveWall)
            convt_kernel<<<dim3(3 * CC_ / 64, CC_ / 64), 256, 0, stream>>>(
                qkv_w + (size_t)l * 3 * C2, wbuf, CC_, 3 * CC_);
        mgemm<0, false, false, false, true><<<dim3(MM_ / 128, 3 * CC_ / 128), 256, 0, stream>>>(
            abuf1, bq, nullptr, nullptr, qkvbuf, MM_, 3 * CC_, CC_);
        // att -> bf16 (flash MFMA attention)
        fattn_kernel<<<dim3(TB_ / 64, BB_ * HH_), 256, 0, stream>>>(qkvbuf, abuf1);
        // x = x + att @ proj_w + proj_b
        if (!haveWall)
            convt_kernel<<<dim3(CC_ / 64, CC_ / 64), 256, 0, stream>>>(
                proj_w + (size_t)l * C2, wbuf, CC_, CC_);
        mgemm<0, true, false, true, false><<<dim3(MM_ / 128, CC_ / 128), 256, 0, stream>>>(
            abuf1, bp, proj_b + l * CC_, x, x, MM_, CC_, CC_);
        // h = LN2(x) -> bf16
        ln_kernel<<<MM_, 256, 0, stream>>>(x, ln2_g + l * CC_, ln2_b + l * CC_, abuf1);
        // hid = gelu(h @ fc1_w + fc1_b) -> bf16
        if (!haveWall)
            convt_kernel<<<dim3(HID_ / 64, CC_ / 64), 256, 0, stream>>>(
                fc1_w + (size_t)l * 4 * C2, wbuf, CC_, HID_);
        mgemm<0, true, true, false, true><<<dim3(MM_ / 128, HID_ / 128), 256, 0, stream>>>(
            abuf1, b1, fc1_b + l * HID_, nullptr, abuf2, MM_, HID_, CC_);
        // x = x + hid @ fc2_w + fc2_b
        if (!haveWall)
            convt_kernel<<<dim3(CC_ / 64, HID_ / 64), 256, 0, stream>>>(
                fc2_w + (size_t)l * 4 * C2, wbuf, HID_, CC_);
        mgemm<0, true, false, true, false><<<dim3(MM_ / 128, CC_ / 128), 256, 0, stream>>>(
            abuf2, b2, fc2_b + l * CC_, x, x, MM_, CC_, HID_);
    }
    // final LN + tied lm_head
    ln_kernel<<<MM_, 256, 0, stream>>>(x, lnf_g, lnf_b, abuf1);
    if (haveTemb) {
        // bf16 temb is [V,C] = B^T layout already; fast global_load_lds path
        mgemm<0, false, false, false, false><<<dim3(MM_ / 128, VV_ / 128), 256, 0, stream>>>(
            abuf1, temb, nullptr, nullptr, out, MM_, VV_, CC_);
    } else {
        mgemm<1, false, false, false, false><<<dim3(MM_ / 128, VV_ / 128), 256, 0, stream>>>(
            abuf1, tok_emb, nullptr, nullptr, out, MM_, VV_, CC_);
    }
}